// Round 2
// baseline (2311.973 us; speedup 1.0000x reference)
//
#include <hip/hip_runtime.h>
#include <math.h>

// TMSA: x(8,4,64,64,120) fp32. Windows (2,2,8,8) -> 512 windows x 256 tokens.
// heads=6, head_dim=20. fp32 compute (correctness baseline), chunked to keep
// workspace peak ~110 MB (R1 crashed: 377 MB workspace likely exceeded ws_size).
//
// Workspace (floats):
//   H/TMP  : [0, 15728640)                      LN1 out (partitioned) / fc2 out
//   S      : [15728640, ...)  scratch region:
//     attn phase per chunk (64 windows = 16384 rows):
//       QKVc  at S          : 3 x 16384x120 = 5,898,240
//       XOUTc at S+5898240  : 16384x240     = 3,932,160   (peak 102.2 MB)
//     mlp phase per chunk (32768 rows):
//       H2c   at S          : 32768x120 = 3,932,160
//       HIDc  at S+3932160  : 32768x240 = 7,864,320       (peak 110.1 MB)
//   X2 (post-attn residual, partitioned) lives in d_out during the middle;
//   final remap kernel window-reverses TMP -> d_out.

#define SCALE 0.22360679774997896f   // (20)^-0.5
#define CH_Q  1966080u               // 16384*120, per-chunk q/k/v plane size

// partitioned row r -> global row g
__device__ __forceinline__ int rev_row(int r) {
    int w = r >> 8, t = r & 255;
    int w8 = w & 7, h8 = (w >> 3) & 7, d2 = (w >> 6) & 1, n2 = w >> 7;
    int www = t & 7, hh = (t >> 3) & 7, dd = (t >> 6) & 1, nn = t >> 7;
    int n = n2 * 2 + nn, d = d2 * 2 + dd;
    int Hc = h8 * 8 + hh, Wc = w8 * 8 + www;
    return ((n * 4 + d) << 12) + (Hc << 6) + Wc;
}

// global row g -> partitioned row
__device__ __forceinline__ int part_row(int g) {
    int ww = g & 63, hh = (g >> 6) & 63, d = (g >> 12) & 3, n = g >> 14;
    int w = ((n >> 1) * 2 + (d >> 1)) * 64 + ((hh >> 3) << 3) + (ww >> 3);
    int t = (((n & 1) * 2 + (d & 1)) << 6) + ((hh & 7) << 3) + (ww & 7);
    return (w << 8) + t;
}

__device__ __forceinline__ float gelu_exact(float x) {
    return 0.5f * x * (1.0f + erff(x * 0.70710678118654752f));
}

// ---------------- LayerNorm (C=120), 4 rows/block, 1 wave/row ----------------
template <bool REMAP>
__global__ __launch_bounds__(256) void ln_kernel(const float* __restrict__ in,
                                                 const float* __restrict__ w,
                                                 const float* __restrict__ b,
                                                 float* __restrict__ out) {
    int row  = blockIdx.x * 4 + (threadIdx.x >> 6);
    int lane = threadIdx.x & 63;
    const float* xr = in + (size_t)row * 120;
    float2 v = make_float2(0.f, 0.f);
    if (lane < 60) v = *(const float2*)(xr + lane * 2);
    float s = v.x + v.y;
#pragma unroll
    for (int off = 32; off; off >>= 1) s += __shfl_down(s, off, 64);
    s = __shfl(s, 0, 64);
    float mean = s * (1.f / 120.f);
    float dx = v.x - mean, dy = v.y - mean;
    float q = (lane < 60) ? (dx * dx + dy * dy) : 0.f;
#pragma unroll
    for (int off = 32; off; off >>= 1) q += __shfl_down(q, off, 64);
    q = __shfl(q, 0, 64);
    float rstd = rsqrtf(q * (1.f / 120.f) + 1e-5f);
    int orow = REMAP ? part_row(row) : row;
    if (lane < 60) {
        float2 wv = *(const float2*)(w + lane * 2);
        float2 bv = *(const float2*)(b + lane * 2);
        float2 o;
        o.x = dx * rstd * wv.x + bv.x;
        o.y = dy * rstd * wv.y + bv.y;
        *(float2*)(out + (size_t)orow * 120 + lane * 2) = o;
    }
}

// ---------------- Tiled SGEMM: out = A(MxK) @ W(NxK)^T + bias ----------------
// 64x64 block tile, 4x4 thread tile, BK=8 (K % 8 == 0). Rows are chunk-local;
// m0 = global partitioned row offset of the chunk. Epilogue by MODE:
//  0 QKV scatter (chunk-local)  1 proj(+x residual at rev_row, write X2 at m0+r)
//  2 gelu write  3 multiply into existing  4 fc2 (+residual, caller pre-offsets)
template <int MODE>
__global__ __launch_bounds__(256) void gemm_kernel(const float* __restrict__ A,
                                                   const float* __restrict__ Wt,
                                                   const float* __restrict__ bias,
                                                   int K, int N,
                                                   float* __restrict__ out,
                                                   const float* __restrict__ aux,
                                                   int m0) {
    const int bm = blockIdx.x * 64;
    const int bn = blockIdx.y * 64;
    const int tid = threadIdx.x;
    const int tx = tid & 15, ty = tid >> 4;

    __shared__ __align__(16) float As[8][68];
    __shared__ __align__(16) float Bs[8][68];

    float acc[4][4] = {{0.f}};

    const int lm = tid >> 2;        // 0..63
    const int lk = (tid & 3) * 2;   // 0,2,4,6
    const float* Aptr = A + (size_t)(bm + lm) * K + lk;
    const int wrow = bn + lm;
    const bool wvalid = wrow < N;
    const float* Wptr = Wt + (size_t)wrow * K + lk;

    for (int k0 = 0; k0 < K; k0 += 8) {
        float2 av = *(const float2*)(Aptr + k0);
        float2 bv = wvalid ? *(const float2*)(Wptr + k0) : make_float2(0.f, 0.f);
        As[lk][lm] = av.x; As[lk + 1][lm] = av.y;
        Bs[lk][lm] = bv.x; Bs[lk + 1][lm] = bv.y;
        __syncthreads();
#pragma unroll
        for (int kk = 0; kk < 8; ++kk) {
            const float4 a4 = *(const float4*)(&As[kk][ty * 4]);
            const float4 b4 = *(const float4*)(&Bs[kk][tx * 4]);
            float av_[4] = {a4.x, a4.y, a4.z, a4.w};
            float bv_[4] = {b4.x, b4.y, b4.z, b4.w};
#pragma unroll
            for (int i = 0; i < 4; ++i)
#pragma unroll
                for (int j = 0; j < 4; ++j) acc[i][j] += av_[i] * bv_[j];
        }
        __syncthreads();
    }

#pragma unroll
    for (int i = 0; i < 4; ++i) {
        int r = bm + ty * 4 + i;    // chunk-local row
        int g = 0;
        if (MODE == 1) g = rev_row(m0 + r);
#pragma unroll
        for (int j = 0; j < 4; ++j) {
            int n = bn + tx * 4 + j;
            if (n >= N) continue;
            float val = acc[i][j] + bias[n];
            if (MODE == 0) {
                int wl = r >> 8, t = r & 255;
                int which = n / 120, hn = n % 120;
                int head = hn / 20, e = hn % 20;
                out[(size_t)which * CH_Q + (((size_t)(wl * 6 + head) * 256 + t) * 20 + e)] = val;
            } else if (MODE == 1) {
                val += aux[(size_t)g * 120 + n];
                out[(size_t)(m0 + r) * 120 + n] = val;
            } else if (MODE == 2) {
                out[(size_t)r * N + n] = gelu_exact(val);
            } else if (MODE == 3) {
                size_t idx = (size_t)r * N + n;
                out[idx] = out[idx] * val;
            } else { // MODE 4: caller pre-offset out/aux by m0*120
                val += aux[(size_t)r * 120 + n];
                out[(size_t)r * 120 + n] = val;
            }
        }
    }
}

// ---------------- Self attention: block = (local window, head), 256 tokens --
__global__ __launch_bounds__(256) void attn_self(const float* __restrict__ qkv,
                                                 float* __restrict__ xout) {
    int w = blockIdx.x / 6, hd = blockIdx.x % 6;
    int t = threadIdx.x;
    __shared__ __align__(16) float ks[256 * 20];
    __shared__ __align__(16) float vs[256 * 20];
    const float* base = qkv + (size_t)((w * 6 + hd) * 256) * 20;
    const float* qp = base + (size_t)t * 20;
    const float* kp = base + CH_Q + (size_t)t * 20;
    const float* vp = base + 2u * CH_Q + (size_t)t * 20;
    float q[20];
#pragma unroll
    for (int e = 0; e < 20; ++e) q[e] = qp[e] * SCALE;
#pragma unroll
    for (int e = 0; e < 20; ++e) { ks[t * 20 + e] = kp[e]; vs[t * 20 + e] = vp[e]; }
    __syncthreads();

    float m = -1e30f, l = 0.f, o[20] = {0.f};
    for (int j0 = 0; j0 < 256; j0 += 16) {
        float s[16];
        float mloc = -1e30f;
#pragma unroll
        for (int jj = 0; jj < 16; ++jj) {
            const float4* kr = (const float4*)&ks[(j0 + jj) * 20];
            float acc = 0.f;
#pragma unroll
            for (int e4 = 0; e4 < 5; ++e4) {
                float4 kk = kr[e4];
                acc += q[e4 * 4 + 0] * kk.x + q[e4 * 4 + 1] * kk.y +
                       q[e4 * 4 + 2] * kk.z + q[e4 * 4 + 3] * kk.w;
            }
            s[jj] = acc;
            mloc = fmaxf(mloc, acc);
        }
        float mnew = fmaxf(m, mloc);
        float alpha = __expf(m - mnew);
        l *= alpha;
#pragma unroll
        for (int e = 0; e < 20; ++e) o[e] *= alpha;
#pragma unroll
        for (int jj = 0; jj < 16; ++jj) {
            float p = __expf(s[jj] - mnew);
            l += p;
            const float4* vr = (const float4*)&vs[(j0 + jj) * 20];
#pragma unroll
            for (int e4 = 0; e4 < 5; ++e4) {
                float4 vv = vr[e4];
                o[e4 * 4 + 0] += p * vv.x; o[e4 * 4 + 1] += p * vv.y;
                o[e4 * 4 + 2] += p * vv.z; o[e4 * 4 + 3] += p * vv.w;
            }
        }
        m = mnew;
    }
    float inv = 1.f / l;
    float* op = xout + (size_t)(w * 256 + t) * 240 + 120 + hd * 20;
#pragma unroll
    for (int e = 0; e < 20; ++e) op[e] = o[e] * inv;
}

// ---------------- Mutual attention: block = (local window, head, half) ------
// out half 0 (t 0..128):   queries tok 128..256, K/V tok 0..128
// out half 1 (t 128..256): queries tok 0..128,   K/V tok 128..256
__global__ __launch_bounds__(128) void attn_mut(const float* __restrict__ qkv,
                                                float* __restrict__ xout) {
    int b = blockIdx.x;
    int half = b & 1, hd = (b >> 1) % 6, w = b / 12;
    int tl = threadIdx.x;
    __shared__ __align__(16) float ks[128 * 20];
    __shared__ __align__(16) float vs[128 * 20];
    const float* base = qkv + (size_t)((w * 6 + hd) * 256) * 20;
    int qtok = (1 - half) * 128 + tl;
    int kv0 = half * 128;
    const float* qp = base + (size_t)qtok * 20;
    const float* kp = base + CH_Q + (size_t)(kv0 + tl) * 20;
    const float* vp = base + 2u * CH_Q + (size_t)(kv0 + tl) * 20;
    float q[20];
#pragma unroll
    for (int e = 0; e < 20; ++e) q[e] = qp[e] * SCALE;
#pragma unroll
    for (int e = 0; e < 20; ++e) { ks[tl * 20 + e] = kp[e]; vs[tl * 20 + e] = vp[e]; }
    __syncthreads();

    float m = -1e30f, l = 0.f, o[20] = {0.f};
    for (int j0 = 0; j0 < 128; j0 += 16) {
        float s[16];
        float mloc = -1e30f;
#pragma unroll
        for (int jj = 0; jj < 16; ++jj) {
            const float4* kr = (const float4*)&ks[(j0 + jj) * 20];
            float acc = 0.f;
#pragma unroll
            for (int e4 = 0; e4 < 5; ++e4) {
                float4 kk = kr[e4];
                acc += q[e4 * 4 + 0] * kk.x + q[e4 * 4 + 1] * kk.y +
                       q[e4 * 4 + 2] * kk.z + q[e4 * 4 + 3] * kk.w;
            }
            s[jj] = acc;
            mloc = fmaxf(mloc, acc);
        }
        float mnew = fmaxf(m, mloc);
        float alpha = __expf(m - mnew);
        l *= alpha;
#pragma unroll
        for (int e = 0; e < 20; ++e) o[e] *= alpha;
#pragma unroll
        for (int jj = 0; jj < 16; ++jj) {
            float p = __expf(s[jj] - mnew);
            l += p;
            const float4* vr = (const float4*)&vs[(j0 + jj) * 20];
#pragma unroll
            for (int e4 = 0; e4 < 5; ++e4) {
                float4 vv = vr[e4];
                o[e4 * 4 + 0] += p * vv.x; o[e4 * 4 + 1] += p * vv.y;
                o[e4 * 4 + 2] += p * vv.z; o[e4 * 4 + 3] += p * vv.w;
            }
        }
        m = mnew;
    }
    float inv = 1.f / l;
    int tout = half * 128 + tl;
    float* op = xout + (size_t)(w * 256 + tout) * 240 + hd * 20;
#pragma unroll
    for (int e = 0; e < 20; ++e) op[e] = o[e] * inv;
}

// -------- Final remap: TMP (partitioned rows) -> d_out (global rows) --------
__global__ __launch_bounds__(256) void remap_out(const float* __restrict__ tmp,
                                                 float* __restrict__ out) {
    int idx = blockIdx.x * 256 + threadIdx.x;   // 131072*60 threads, float2 each
    int r = idx / 60, p = idx % 60;
    int g = rev_row(r);
    *(float2*)(out + (size_t)g * 120 + p * 2) =
        *(const float2*)(tmp + (size_t)r * 120 + p * 2);
}

extern "C" void kernel_launch(void* const* d_in, const int* in_sizes, int n_in,
                              void* d_out, int out_size, void* d_ws, size_t ws_size,
                              hipStream_t stream) {
    const float* x          = (const float*)d_in[0];
    const float* norm1_w    = (const float*)d_in[1];
    const float* norm1_b    = (const float*)d_in[2];
    const float* qkv_self_w = (const float*)d_in[3];
    const float* qkv_self_b = (const float*)d_in[4];
    const float* qkv_mut_w  = (const float*)d_in[5];
    const float* qkv_mut_b  = (const float*)d_in[6];
    const float* proj_w     = (const float*)d_in[7];
    const float* proj_b     = (const float*)d_in[8];
    const float* norm2_w    = (const float*)d_in[9];
    const float* norm2_b    = (const float*)d_in[10];
    const float* fc11_w     = (const float*)d_in[11];
    const float* fc11_b     = (const float*)d_in[12];
    const float* fc12_w     = (const float*)d_in[13];
    const float* fc12_b     = (const float*)d_in[14];
    const float* fc2_w      = (const float*)d_in[15];
    const float* fc2_b      = (const float*)d_in[16];

    // Workspace budget: 27,525,120 floats = 110,100,480 bytes.
    if (ws_size < 27525120u * sizeof(float)) return;  // clean fail > segfault

    float* ws    = (float*)d_ws;
    float* H     = ws;                     // 15,728,640 (also TMP in MLP phase)
    float* S     = ws + 15728640u;
    float* QKVc  = S;                      // 5,898,240
    float* XOUTc = S + 5898240u;           // 3,932,160
    float* H2c   = S;                      // 3,932,160 (MLP phase)
    float* HIDc  = S + 3932160u;           // 7,864,320 (MLP phase)
    float* X2    = (float*)d_out;          // partitioned residual, mid-pipeline
    float* TMP   = H;

    // 1. LN1 + window partition (full tensor)
    ln_kernel<true><<<32768, 256, 0, stream>>>(x, norm1_w, norm1_b, H);

    // 2. Attention phase: 8 chunks x 64 windows (16384 rows)
    for (int c = 0; c < 8; ++c) {
        int m0 = c * 16384;
        const float* Ac = H + (size_t)m0 * 120;
        gemm_kernel<0><<<dim3(256, 6), 256, 0, stream>>>(Ac, qkv_self_w, qkv_self_b,
                                                         120, 360, QKVc, nullptr, 0);
        attn_self<<<384, 256, 0, stream>>>(QKVc, XOUTc);
        gemm_kernel<0><<<dim3(256, 6), 256, 0, stream>>>(Ac, qkv_mut_w, qkv_mut_b,
                                                         120, 360, QKVc, nullptr, 0);
        attn_mut<<<768, 128, 0, stream>>>(QKVc, XOUTc);
        gemm_kernel<1><<<dim3(256, 2), 256, 0, stream>>>(XOUTc, proj_w, proj_b,
                                                         240, 120, X2, x, m0);
    }

    // 3. MLP phase: 4 chunks x 32768 rows
    for (int c = 0; c < 4; ++c) {
        int m0 = c * 32768;
        ln_kernel<false><<<8192, 256, 0, stream>>>(X2 + (size_t)m0 * 120,
                                                   norm2_w, norm2_b, H2c);
        gemm_kernel<2><<<dim3(512, 4), 256, 0, stream>>>(H2c, fc11_w, fc11_b,
                                                         120, 240, HIDc, nullptr, 0);
        gemm_kernel<3><<<dim3(512, 4), 256, 0, stream>>>(H2c, fc12_w, fc12_b,
                                                         120, 240, HIDc, nullptr, 0);
        gemm_kernel<4><<<dim3(512, 2), 256, 0, stream>>>(HIDc, fc2_w, fc2_b,
                                                         240, 120,
                                                         TMP + (size_t)m0 * 120,
                                                         X2 + (size_t)m0 * 120, 0);
    }

    // 4. Window-reverse TMP -> d_out
    remap_out<<<30720, 256, 0, stream>>>(TMP, (float*)d_out);
}

// Round 3
// 1182.244 us; speedup vs baseline: 1.9556x; 1.9556x over previous
//
#include <hip/hip_runtime.h>
#include <hip/hip_bf16.h>
#include <math.h>

// TMSA bf16 round: MFMA GEMMs (LDS-free, direct-global fragments) + bf16
// activations. Attention chunked at 256 windows (grids 1536/3072) for
// occupancy; compute fp32 VALU with K/V staged to LDS as fp32.
//
// ws layout (bytes), guard 110,100,480:
//   attn phase: Hb bf16 [0,31457280) | QKVc bf16 [31457280,78643200)
//               XOUTc bf16 [78643200,110100480)
//   mlp  phase: TMP fp32 [0,62914560) | H2c bf16 [62914560,78643200)
//               HIDc bf16 [78643200,110100480)
//   X2 (fp32, partitioned residual) lives in d_out; final remap TMP->d_out.

typedef __attribute__((ext_vector_type(8))) short bf16x8;
typedef __attribute__((ext_vector_type(4))) float f32x4;

#define SCALE  0.22360679774997896f   // (20)^-0.5
#define CHROWS 65536                  // rows per attention chunk (256 windows)
#define QPLANE 7864320u               // CHROWS*120, per-chunk q/k/v plane elems

__device__ __forceinline__ short bf16b(float f) {
    __hip_bfloat16 h = __float2bfloat16(f);
    return *reinterpret_cast<short*>(&h);
}
__device__ __forceinline__ float bf2f(short s) {
    return __uint_as_float(((unsigned)(unsigned short)s) << 16);
}
__device__ __forceinline__ unsigned packbf(float a, float b) {
    return (unsigned)(unsigned short)bf16b(a) |
           ((unsigned)(unsigned short)bf16b(b) << 16);
}

// partitioned row r -> global row g
__device__ __forceinline__ int rev_row(int r) {
    int w = r >> 8, t = r & 255;
    int w8 = w & 7, h8 = (w >> 3) & 7, d2 = (w >> 6) & 1, n2 = w >> 7;
    int www = t & 7, hh = (t >> 3) & 7, dd = (t >> 6) & 1, nn = t >> 7;
    int n = n2 * 2 + nn, d = d2 * 2 + dd;
    int Hc = h8 * 8 + hh, Wc = w8 * 8 + www;
    return ((n * 4 + d) << 12) + (Hc << 6) + Wc;
}
// global row g -> partitioned row
__device__ __forceinline__ int part_row(int g) {
    int ww = g & 63, hh = (g >> 6) & 63, d = (g >> 12) & 3, n = g >> 14;
    int w = ((n >> 1) * 2 + (d >> 1)) * 64 + ((hh >> 3) << 3) + (ww >> 3);
    int t = (((n & 1) * 2 + (d & 1)) << 6) + ((hh & 7) << 3) + (ww & 7);
    return (w << 8) + t;
}
__device__ __forceinline__ float gelu_exact(float x) {
    return 0.5f * x * (1.0f + erff(x * 0.70710678118654752f));
}
// 20 bf16 (8-B aligned) -> 20 fp32
__device__ __forceinline__ void load20(const short* p, float* dst) {
    const uint2* q = (const uint2*)p;
#pragma unroll
    for (int i = 0; i < 5; ++i) {
        uint2 u = q[i];
        dst[i * 4 + 0] = __uint_as_float(u.x << 16);
        dst[i * 4 + 1] = __uint_as_float(u.x & 0xffff0000u);
        dst[i * 4 + 2] = __uint_as_float(u.y << 16);
        dst[i * 4 + 3] = __uint_as_float(u.y & 0xffff0000u);
    }
}

// ---------------- LayerNorm (C=120) fp32 in -> bf16 out ---------------------
template <bool REMAP>
__global__ __launch_bounds__(256) void ln_kernel(const float* __restrict__ in,
                                                 const float* __restrict__ w,
                                                 const float* __restrict__ b,
                                                 short* __restrict__ out) {
    int row  = blockIdx.x * 4 + (threadIdx.x >> 6);
    int lane = threadIdx.x & 63;
    const float* xr = in + (size_t)row * 120;
    float2 v = make_float2(0.f, 0.f);
    if (lane < 60) v = *(const float2*)(xr + lane * 2);
    float s = v.x + v.y;
#pragma unroll
    for (int off = 32; off; off >>= 1) s += __shfl_down(s, off, 64);
    s = __shfl(s, 0, 64);
    float mean = s * (1.f / 120.f);
    float dx = v.x - mean, dy = v.y - mean;
    float q = (lane < 60) ? (dx * dx + dy * dy) : 0.f;
#pragma unroll
    for (int off = 32; off; off >>= 1) q += __shfl_down(q, off, 64);
    q = __shfl(q, 0, 64);
    float rstd = rsqrtf(q * (1.f / 120.f) + 1e-5f);
    int orow = REMAP ? part_row(row) : row;
    if (lane < 60) {
        float2 wv = *(const float2*)(w + lane * 2);
        float2 bv = *(const float2*)(b + lane * 2);
        unsigned u = packbf(dx * rstd * wv.x + bv.x, dy * rstd * wv.y + bv.y);
        *(unsigned*)(out + (size_t)orow * 120 + lane * 2) = u;
    }
}

// ------------- MFMA GEMM: out = A(M x K, bf16) @ W(N x K, fp32)^T + bias ----
// LDS-free: A-frag = lane(m=lane&15) 8 contiguous k -> one b128 global load;
// B-frag = lane(n=lane&15) 8 contiguous k from W row (fp32 -> bf16 inline).
// Block 256 thr = 2x2 waves, tile 128x64; wave tile 64x32 (4 m-frags x 2 n).
// MODE: 0 QKV scatter | 1 proj(+x res @rev_row -> X2 fp32) | 2 gelu bf16
//       3 multiply-into bf16 | 4 fc2(+X2 res -> TMP fp32)
template <int MODE, int K, int N>
__global__ __launch_bounds__(256) void mm(const short* __restrict__ A,
                                          const float* __restrict__ W,
                                          const float* __restrict__ bias,
                                          void* __restrict__ outp,
                                          const float* __restrict__ aux,
                                          int m0) {
    const int lane = threadIdx.x & 63, wave = threadIdx.x >> 6;
    const int quad = lane >> 4, l16 = lane & 15;
    const int bm = blockIdx.x * 128 + (wave >> 1) * 64;
    const int bn = blockIdx.y * 64 + (wave & 1) * 32;

    f32x4 acc[4][2];
#pragma unroll
    for (int i = 0; i < 4; ++i)
#pragma unroll
        for (int j = 0; j < 2; ++j) acc[i][j] = (f32x4){0.f, 0.f, 0.f, 0.f};

    const short* Ar[4];
#pragma unroll
    for (int i = 0; i < 4; ++i) Ar[i] = A + (size_t)(bm + i * 16 + l16) * K;
    const int n0 = bn + l16, n1 = bn + 16 + l16;
    const int nc0 = n0 < N ? n0 : N - 1;
    const int nc1 = n1 < N ? n1 : N - 1;
    const float* W0 = W + (size_t)nc0 * K;
    const float* W1 = W + (size_t)nc1 * K;

    const int KT = (K + 31) / 32;
#pragma unroll
    for (int kt = 0; kt < KT; ++kt) {
        int kk = kt * 32 + quad * 8;
        bool kok = kk < K;
        int kc = kok ? kk : 0;
        bf16x8 a[4], b0v, b1v;
#pragma unroll
        for (int i = 0; i < 4; ++i) a[i] = *(const bf16x8*)(Ar[i] + kc);
        {
            f32x4 w0 = *(const f32x4*)(W0 + kc);
            f32x4 w1 = *(const f32x4*)(W0 + kc + 4);
            b0v = (bf16x8){bf16b(w0.x), bf16b(w0.y), bf16b(w0.z), bf16b(w0.w),
                           bf16b(w1.x), bf16b(w1.y), bf16b(w1.z), bf16b(w1.w)};
            f32x4 w2 = *(const f32x4*)(W1 + kc);
            f32x4 w3 = *(const f32x4*)(W1 + kc + 4);
            b1v = (bf16x8){bf16b(w2.x), bf16b(w2.y), bf16b(w2.z), bf16b(w2.w),
                           bf16b(w3.x), bf16b(w3.y), bf16b(w3.z), bf16b(w3.w)};
        }
        if (!kok) {
            bf16x8 zz = {0, 0, 0, 0, 0, 0, 0, 0};
            a[0] = a[1] = a[2] = a[3] = b0v = b1v = zz;
        }
#pragma unroll
        for (int i = 0; i < 4; ++i) {
            acc[i][0] = __builtin_amdgcn_mfma_f32_16x16x32_bf16(a[i], b0v, acc[i][0], 0, 0, 0);
            acc[i][1] = __builtin_amdgcn_mfma_f32_16x16x32_bf16(a[i], b1v, acc[i][1], 0, 0, 0);
        }
    }

#pragma unroll
    for (int j = 0; j < 2; ++j) {
        const int n = j ? n1 : n0;
        if (n >= N) continue;
        const float bs = bias[n];
        // mode-0 decode (hoisted; n is per-lane constant)
        int which = 0, head = 0, e = 0;
        if (MODE == 0) { which = n / 120; int hn = n % 120; head = hn / 20; e = hn % 20; }
#pragma unroll
        for (int i = 0; i < 4; ++i) {
#pragma unroll
            for (int r = 0; r < 4; ++r) {
                int m = bm + i * 16 + quad * 4 + r;
                float val = acc[i][j][r] + bs;
                if (MODE == 0) {
                    int wl = m >> 8, t = m & 255;
                    ((short*)outp)[(size_t)which * QPLANE +
                                   ((size_t)((wl * 6 + head) * 256 + t)) * 20 + e] = bf16b(val);
                } else if (MODE == 1) {
                    int g = rev_row(m0 + m);
                    val += aux[(size_t)g * 120 + n];
                    ((float*)outp)[(size_t)(m0 + m) * 120 + n] = val;
                } else if (MODE == 2) {
                    ((short*)outp)[(size_t)m * 240 + n] = bf16b(gelu_exact(val));
                } else if (MODE == 3) {
                    size_t idx = (size_t)m * 240 + n;
                    short* o = (short*)outp;
                    o[idx] = bf16b(bf2f(o[idx]) * val);
                } else { // MODE 4
                    val += aux[(size_t)(m0 + m) * 120 + n];
                    ((float*)outp)[(size_t)(m0 + m) * 120 + n] = val;
                }
            }
        }
    }
}

// ---------------- Self attention: block = (local window, head) --------------
__global__ __launch_bounds__(256) void attn_self(const short* __restrict__ qkv,
                                                 short* __restrict__ xout) {
    int wl = blockIdx.x / 6, hd = blockIdx.x % 6;
    int t = threadIdx.x;
    __shared__ __align__(16) float ks[256 * 20];
    __shared__ __align__(16) float vs[256 * 20];
    const short* base = qkv + ((size_t)(wl * 6 + hd) * 256) * 20;
    float q[20], kr[20], vr[20];
    load20(base + (size_t)t * 20, q);
    load20(base + QPLANE + (size_t)t * 20, kr);
    load20(base + 2u * QPLANE + (size_t)t * 20, vr);
#pragma unroll
    for (int e = 0; e < 20; ++e) { q[e] *= SCALE; ks[t * 20 + e] = kr[e]; vs[t * 20 + e] = vr[e]; }
    __syncthreads();

    float m = -1e30f, l = 0.f, o[20] = {0.f};
    for (int j0 = 0; j0 < 256; j0 += 16) {
        float s[16];
        float mloc = -1e30f;
#pragma unroll
        for (int jj = 0; jj < 16; ++jj) {
            const float4* krp = (const float4*)&ks[(j0 + jj) * 20];
            float acc = 0.f;
#pragma unroll
            for (int e4 = 0; e4 < 5; ++e4) {
                float4 kk = krp[e4];
                acc += q[e4 * 4 + 0] * kk.x + q[e4 * 4 + 1] * kk.y +
                       q[e4 * 4 + 2] * kk.z + q[e4 * 4 + 3] * kk.w;
            }
            s[jj] = acc;
            mloc = fmaxf(mloc, acc);
        }
        float mnew = fmaxf(m, mloc);
        float alpha = __expf(m - mnew);
        l *= alpha;
#pragma unroll
        for (int e = 0; e < 20; ++e) o[e] *= alpha;
#pragma unroll
        for (int jj = 0; jj < 16; ++jj) {
            float p = __expf(s[jj] - mnew);
            l += p;
            const float4* vrp = (const float4*)&vs[(j0 + jj) * 20];
#pragma unroll
            for (int e4 = 0; e4 < 5; ++e4) {
                float4 vv = vrp[e4];
                o[e4 * 4 + 0] += p * vv.x; o[e4 * 4 + 1] += p * vv.y;
                o[e4 * 4 + 2] += p * vv.z; o[e4 * 4 + 3] += p * vv.w;
            }
        }
        m = mnew;
    }
    float inv = 1.f / l;
    unsigned* op = (unsigned*)(xout + (size_t)(wl * 256 + t) * 240 + 120 + hd * 20);
#pragma unroll
    for (int i = 0; i < 10; ++i) op[i] = packbf(o[2 * i] * inv, o[2 * i + 1] * inv);
}

// ---------------- Mutual attention: block = (local window, head, half) ------
__global__ __launch_bounds__(128) void attn_mut(const short* __restrict__ qkv,
                                                short* __restrict__ xout) {
    int b = blockIdx.x;
    int half = b & 1, hd = (b >> 1) % 6, wl = b / 12;
    int tl = threadIdx.x;
    __shared__ __align__(16) float ks[128 * 20];
    __shared__ __align__(16) float vs[128 * 20];
    const short* base = qkv + ((size_t)(wl * 6 + hd) * 256) * 20;
    int qtok = (1 - half) * 128 + tl;
    int kv0 = half * 128;
    float q[20], kr[20], vr[20];
    load20(base + (size_t)qtok * 20, q);
    load20(base + QPLANE + (size_t)(kv0 + tl) * 20, kr);
    load20(base + 2u * QPLANE + (size_t)(kv0 + tl) * 20, vr);
#pragma unroll
    for (int e = 0; e < 20; ++e) { q[e] *= SCALE; ks[tl * 20 + e] = kr[e]; vs[tl * 20 + e] = vr[e]; }
    __syncthreads();

    float m = -1e30f, l = 0.f, o[20] = {0.f};
    for (int j0 = 0; j0 < 128; j0 += 16) {
        float s[16];
        float mloc = -1e30f;
#pragma unroll
        for (int jj = 0; jj < 16; ++jj) {
            const float4* krp = (const float4*)&ks[(j0 + jj) * 20];
            float acc = 0.f;
#pragma unroll
            for (int e4 = 0; e4 < 5; ++e4) {
                float4 kk = krp[e4];
                acc += q[e4 * 4 + 0] * kk.x + q[e4 * 4 + 1] * kk.y +
                       q[e4 * 4 + 2] * kk.z + q[e4 * 4 + 3] * kk.w;
            }
            s[jj] = acc;
            mloc = fmaxf(mloc, acc);
        }
        float mnew = fmaxf(m, mloc);
        float alpha = __expf(m - mnew);
        l *= alpha;
#pragma unroll
        for (int e = 0; e < 20; ++e) o[e] *= alpha;
#pragma unroll
        for (int jj = 0; jj < 16; ++jj) {
            float p = __expf(s[jj] - mnew);
            l += p;
            const float4* vrp = (const float4*)&vs[(j0 + jj) * 20];
#pragma unroll
            for (int e4 = 0; e4 < 5; ++e4) {
                float4 vv = vrp[e4];
                o[e4 * 4 + 0] += p * vv.x; o[e4 * 4 + 1] += p * vv.y;
                o[e4 * 4 + 2] += p * vv.z; o[e4 * 4 + 3] += p * vv.w;
            }
        }
        m = mnew;
    }
    float inv = 1.f / l;
    int tout = half * 128 + tl;
    unsigned* op = (unsigned*)(xout + (size_t)(wl * 256 + tout) * 240 + hd * 20);
#pragma unroll
    for (int i = 0; i < 10; ++i) op[i] = packbf(o[2 * i] * inv, o[2 * i + 1] * inv);
}

// -------- Final remap: TMP fp32 (partitioned rows) -> d_out (global rows) ---
__global__ __launch_bounds__(256) void remap_out(const float* __restrict__ tmp,
                                                 float* __restrict__ out) {
    int idx = blockIdx.x * 256 + threadIdx.x;
    int r = idx / 60, p = idx % 60;
    int g = rev_row(r);
    *(float2*)(out + (size_t)g * 120 + p * 2) =
        *(const float2*)(tmp + (size_t)r * 120 + p * 2);
}

extern "C" void kernel_launch(void* const* d_in, const int* in_sizes, int n_in,
                              void* d_out, int out_size, void* d_ws, size_t ws_size,
                              hipStream_t stream) {
    const float* x          = (const float*)d_in[0];
    const float* norm1_w    = (const float*)d_in[1];
    const float* norm1_b    = (const float*)d_in[2];
    const float* qkv_self_w = (const float*)d_in[3];
    const float* qkv_self_b = (const float*)d_in[4];
    const float* qkv_mut_w  = (const float*)d_in[5];
    const float* qkv_mut_b  = (const float*)d_in[6];
    const float* proj_w     = (const float*)d_in[7];
    const float* proj_b     = (const float*)d_in[8];
    const float* norm2_w    = (const float*)d_in[9];
    const float* norm2_b    = (const float*)d_in[10];
    const float* fc11_w     = (const float*)d_in[11];
    const float* fc11_b     = (const float*)d_in[12];
    const float* fc12_w     = (const float*)d_in[13];
    const float* fc12_b     = (const float*)d_in[14];
    const float* fc2_w      = (const float*)d_in[15];
    const float* fc2_b      = (const float*)d_in[16];

    if (ws_size < 110100480u) return;  // proven-good budget from R2

    char* wsb   = (char*)d_ws;
    short* Hb    = (short*)wsb;                  // 131072x120 bf16
    short* QKVc  = (short*)(wsb + 31457280);     // 3 x 65536x120 bf16
    short* XOUTc = (short*)(wsb + 78643200);     // 65536x240 bf16
    float* TMP   = (float*)wsb;                  // 131072x120 fp32 (MLP phase)
    short* H2c   = (short*)(wsb + 62914560);     // 65536x120 bf16
    short* HIDc  = (short*)(wsb + 78643200);     // 65536x240 bf16
    float* X2    = (float*)d_out;                // partitioned residual fp32

    // 1. LN1 + window partition -> Hb (bf16)
    ln_kernel<true><<<32768, 256, 0, stream>>>(x, norm1_w, norm1_b, Hb);

    // 2. Attention phase: 2 chunks x 256 windows (65536 rows)
    for (int c = 0; c < 2; ++c) {
        int m0 = c * CHROWS;
        const short* Ac = Hb + (size_t)m0 * 120;
        mm<0, 120, 360><<<dim3(512, 6), 256, 0, stream>>>(Ac, qkv_self_w, qkv_self_b,
                                                          QKVc, nullptr, 0);
        attn_self<<<1536, 256, 0, stream>>>(QKVc, XOUTc);
        mm<0, 120, 360><<<dim3(512, 6), 256, 0, stream>>>(Ac, qkv_mut_w, qkv_mut_b,
                                                          QKVc, nullptr, 0);
        attn_mut<<<3072, 128, 0, stream>>>(QKVc, XOUTc);
        mm<1, 240, 120><<<dim3(512, 2), 256, 0, stream>>>(XOUTc, proj_w, proj_b,
                                                          X2, x, m0);
    }

    // 3. MLP phase: 2 chunks x 65536 rows
    for (int c = 0; c < 2; ++c) {
        int m0 = c * CHROWS;
        ln_kernel<false><<<16384, 256, 0, stream>>>(X2 + (size_t)m0 * 120,
                                                    norm2_w, norm2_b, H2c);
        mm<2, 120, 240><<<dim3(512, 4), 256, 0, stream>>>(H2c, fc11_w, fc11_b,
                                                          HIDc, nullptr, 0);
        mm<3, 120, 240><<<dim3(512, 4), 256, 0, stream>>>(H2c, fc12_w, fc12_b,
                                                          HIDc, nullptr, 0);
        mm<4, 240, 120><<<dim3(512, 2), 256, 0, stream>>>(HIDc, fc2_w, fc2_b,
                                                          TMP, X2, m0);
    }

    // 4. Window-reverse TMP -> d_out
    remap_out<<<30720, 256, 0, stream>>>(TMP, (float*)d_out);
}

// Round 4
// 836.855 us; speedup vs baseline: 2.7627x; 1.4127x over previous
//
#include <hip/hip_runtime.h>
#include <hip/hip_bf16.h>
#include <math.h>

// TMSA: MFMA flash attention round.
// - GEMMs: LDS-free MFMA (verified R3).
// - Attention: per-(window,head) flash with S^T trick:
//     S^T = mfma(A=K, B=Q)  -> C layout col(l16)=query, row(quad*4+reg)=key
//     row stats: in-lane max/sum over 8 regs + shfl_xor(16,32)  (1 scalar/lane)
//     P^T -> PV B-frag via 8 bpermute + 4 cndmask (no LDS round trip)
//     O^T = mfma(A=V^T from LDS, B=P^T), epilogue divides by l, writes bf16.
// - softmax scale*log2e folded into q at the QKV-GEMM epilogue (exp2 inner loop).
//
// ws layout (bytes), guard 110,100,480:
//   attn phase: Hb bf16 [0,31457280) | QKVc bf16 [31457280,78643200)
//               XOUTc bf16 [78643200,110100480)
//   mlp  phase: TMP fp32 [0,62914560) | H2c bf16 [62914560,78643200)
//               HIDc bf16 [78643200,110100480)
//   X2 (fp32, partitioned residual) lives in d_out; final remap TMP->d_out.

typedef __attribute__((ext_vector_type(8))) short bf16x8;
typedef __attribute__((ext_vector_type(4))) float f32x4;

#define SCALE2 (0.22360679774997896f * 1.44269504088896340f)  // d^-0.5 * log2(e)
#define CHROWS 65536
#define QPLANE 7864320u   // 65536*120 elems per q/k/v plane (chunk)

union B8U { bf16x8 v; uint2 u2[2]; unsigned u[4]; short s[8]; };

__device__ __forceinline__ short bf16b(float f) {
    __hip_bfloat16 h = __float2bfloat16(f);
    return *reinterpret_cast<short*>(&h);
}
__device__ __forceinline__ float bf2f(short s) {
    return __uint_as_float(((unsigned)(unsigned short)s) << 16);
}
__device__ __forceinline__ unsigned packbf(float a, float b) {
    return (unsigned)(unsigned short)bf16b(a) |
           ((unsigned)(unsigned short)bf16b(b) << 16);
}

// partitioned row r -> global row g
__device__ __forceinline__ int rev_row(int r) {
    int w = r >> 8, t = r & 255;
    int w8 = w & 7, h8 = (w >> 3) & 7, d2 = (w >> 6) & 1, n2 = w >> 7;
    int www = t & 7, hh = (t >> 3) & 7, dd = (t >> 6) & 1, nn = t >> 7;
    int n = n2 * 2 + nn, d = d2 * 2 + dd;
    int Hc = h8 * 8 + hh, Wc = w8 * 8 + www;
    return ((n * 4 + d) << 12) + (Hc << 6) + Wc;
}
// global row g -> partitioned row
__device__ __forceinline__ int part_row(int g) {
    int ww = g & 63, hh = (g >> 6) & 63, d = (g >> 12) & 3, n = g >> 14;
    int w = ((n >> 1) * 2 + (d >> 1)) * 64 + ((hh >> 3) << 3) + (ww >> 3);
    int t = (((n & 1) * 2 + (d & 1)) << 6) + ((hh & 7) << 3) + (ww & 7);
    return (w << 8) + t;
}
__device__ __forceinline__ float gelu_exact(float x) {
    return 0.5f * x * (1.0f + erff(x * 0.70710678118654752f));
}

// load A/B-frag from a 20-elem bf16 row (stride 20), k = quad*8..quad*8+7,
// zero-padded for k >= 20. 8B-aligned uint2 loads (row byte offset % 8 == 0).
__device__ __forceinline__ bf16x8 load_frag20(const short* row, int quad) {
    B8U r;
    const uint2* p = (const uint2*)(row + quad * 8);
    r.u2[0] = p[0]; r.u2[1] = p[1];
    if (quad == 2) { r.u[2] = 0; r.u[3] = 0; }
    else if (quad == 3) { r.u[0] = r.u[1] = r.u[2] = r.u[3] = 0; }
    return r.v;
}

// ---------------- LayerNorm (C=120) fp32 in -> bf16 out ---------------------
template <bool REMAP>
__global__ __launch_bounds__(256) void ln_kernel(const float* __restrict__ in,
                                                 const float* __restrict__ w,
                                                 const float* __restrict__ b,
                                                 short* __restrict__ out) {
    int row  = blockIdx.x * 4 + (threadIdx.x >> 6);
    int lane = threadIdx.x & 63;
    const float* xr = in + (size_t)row * 120;
    float2 v = make_float2(0.f, 0.f);
    if (lane < 60) v = *(const float2*)(xr + lane * 2);
    float s = v.x + v.y;
#pragma unroll
    for (int off = 32; off; off >>= 1) s += __shfl_down(s, off, 64);
    s = __shfl(s, 0, 64);
    float mean = s * (1.f / 120.f);
    float dx = v.x - mean, dy = v.y - mean;
    float q = (lane < 60) ? (dx * dx + dy * dy) : 0.f;
#pragma unroll
    for (int off = 32; off; off >>= 1) q += __shfl_down(q, off, 64);
    q = __shfl(q, 0, 64);
    float rstd = rsqrtf(q * (1.f / 120.f) + 1e-5f);
    int orow = REMAP ? part_row(row) : row;
    if (lane < 60) {
        float2 wv = *(const float2*)(w + lane * 2);
        float2 bv = *(const float2*)(b + lane * 2);
        unsigned u = packbf(dx * rstd * wv.x + bv.x, dy * rstd * wv.y + bv.y);
        *(unsigned*)(out + (size_t)orow * 120 + lane * 2) = u;
    }
}

// ------------- MFMA GEMM: out = A(M x K, bf16) @ W(N x K, fp32)^T + bias ----
// MODE: 0 QKV scatter (q pre-scaled by SCALE2) | 1 proj(+x res -> X2 fp32)
//       2 gelu bf16 | 3 multiply-into bf16 | 4 fc2(+X2 res -> TMP fp32)
template <int MODE, int K, int N>
__global__ __launch_bounds__(256) void mm(const short* __restrict__ A,
                                          const float* __restrict__ W,
                                          const float* __restrict__ bias,
                                          void* __restrict__ outp,
                                          const float* __restrict__ aux,
                                          int m0) {
    const int lane = threadIdx.x & 63, wave = threadIdx.x >> 6;
    const int quad = lane >> 4, l16 = lane & 15;
    const int bm = blockIdx.x * 128 + (wave >> 1) * 64;
    const int bn = blockIdx.y * 64 + (wave & 1) * 32;

    f32x4 acc[4][2];
#pragma unroll
    for (int i = 0; i < 4; ++i)
#pragma unroll
        for (int j = 0; j < 2; ++j) acc[i][j] = (f32x4){0.f, 0.f, 0.f, 0.f};

    const short* Ar[4];
#pragma unroll
    for (int i = 0; i < 4; ++i) Ar[i] = A + (size_t)(bm + i * 16 + l16) * K;
    const int n0 = bn + l16, n1 = bn + 16 + l16;
    const int nc0 = n0 < N ? n0 : N - 1;
    const int nc1 = n1 < N ? n1 : N - 1;
    const float* W0 = W + (size_t)nc0 * K;
    const float* W1 = W + (size_t)nc1 * K;

    const int KT = (K + 31) / 32;
#pragma unroll
    for (int kt = 0; kt < KT; ++kt) {
        int kk = kt * 32 + quad * 8;
        bool kok = kk < K;
        int kc = kok ? kk : 0;
        bf16x8 a[4], b0v, b1v;
#pragma unroll
        for (int i = 0; i < 4; ++i) a[i] = *(const bf16x8*)(Ar[i] + kc);
        {
            f32x4 w0 = *(const f32x4*)(W0 + kc);
            f32x4 w1 = *(const f32x4*)(W0 + kc + 4);
            b0v = (bf16x8){bf16b(w0.x), bf16b(w0.y), bf16b(w0.z), bf16b(w0.w),
                           bf16b(w1.x), bf16b(w1.y), bf16b(w1.z), bf16b(w1.w)};
            f32x4 w2 = *(const f32x4*)(W1 + kc);
            f32x4 w3 = *(const f32x4*)(W1 + kc + 4);
            b1v = (bf16x8){bf16b(w2.x), bf16b(w2.y), bf16b(w2.z), bf16b(w2.w),
                           bf16b(w3.x), bf16b(w3.y), bf16b(w3.z), bf16b(w3.w)};
        }
        if (!kok) {
            bf16x8 zz = {0, 0, 0, 0, 0, 0, 0, 0};
            a[0] = a[1] = a[2] = a[3] = b0v = b1v = zz;
        }
#pragma unroll
        for (int i = 0; i < 4; ++i) {
            acc[i][0] = __builtin_amdgcn_mfma_f32_16x16x32_bf16(a[i], b0v, acc[i][0], 0, 0, 0);
            acc[i][1] = __builtin_amdgcn_mfma_f32_16x16x32_bf16(a[i], b1v, acc[i][1], 0, 0, 0);
        }
    }

#pragma unroll
    for (int j = 0; j < 2; ++j) {
        const int n = j ? n1 : n0;
        if (n >= N) continue;
        const float bs = bias[n];
        int which = 0, head = 0, e = 0;
        if (MODE == 0) { which = n / 120; int hn = n % 120; head = hn / 20; e = hn % 20; }
#pragma unroll
        for (int i = 0; i < 4; ++i) {
#pragma unroll
            for (int r = 0; r < 4; ++r) {
                int m = bm + i * 16 + quad * 4 + r;
                float val = acc[i][j][r] + bs;
                if (MODE == 0) {
                    if (which == 0) val *= SCALE2;   // fold softmax scale*log2e into q
                    int wl = m >> 8, t = m & 255;
                    ((short*)outp)[(size_t)which * QPLANE +
                                   ((size_t)((wl * 6 + head) * 256 + t)) * 20 + e] = bf16b(val);
                } else if (MODE == 1) {
                    int g = rev_row(m0 + m);
                    val += aux[(size_t)g * 120 + n];
                    ((float*)outp)[(size_t)(m0 + m) * 120 + n] = val;
                } else if (MODE == 2) {
                    ((short*)outp)[(size_t)m * 240 + n] = bf16b(gelu_exact(val));
                } else if (MODE == 3) {
                    size_t idx = (size_t)m * 240 + n;
                    short* o = (short*)outp;
                    o[idx] = bf16b(bf2f(o[idx]) * val);
                } else { // MODE 4
                    val += aux[(size_t)(m0 + m) * 120 + n];
                    ((float*)outp)[(size_t)(m0 + m) * 120 + n] = val;
                }
            }
        }
    }
}

// ---------------- MFMA flash attention ---------------------------------------
// self: NK=256, blockDim 256 (4 waves x 64 queries), grid = nwin*6
// mut:  NK=128, blockDim 128 (2 waves x 64 queries), grid = nwin*6*2
//   half h: queries tok (1-h)*128.., K/V tok h*128.., out tok h*128..
template <int NK, bool MUT>
__global__ __launch_bounds__(NK) void attn_flash(const short* __restrict__ qkv,
                                                 short* __restrict__ xout) {
    constexpr int VSTR = NK + 8;
    __shared__ __align__(16) short Vt[32 * VSTR];
    const int b = blockIdx.x;
    int wl, hd, half;
    if (MUT) { half = b & 1; hd = (b >> 1) % 6; wl = b / 12; }
    else     { half = 0;     hd = b % 6;        wl = b / 6;  }
    const int tid  = threadIdx.x;
    const int lane = tid & 63, wave = tid >> 6;
    const int quad = lane >> 4, l16 = lane & 15;

    const size_t rb = (size_t)(wl * 6 + hd) * 256;
    const short* qpl = qkv + rb * 20;
    const short* kpl = qkv + (size_t)QPLANE + rb * 20;
    const short* vpl = qkv + 2 * (size_t)QPLANE + rb * 20;
    const int koff = MUT ? half * 128 : 0;
    const int qoff = MUT ? (1 - half) * 128 : 0;

    // stage V^T into LDS: Vt[dim][key], dims 20..31 zero
    {
        const short* vr = vpl + (size_t)(koff + tid) * 20;
        short tmp[20];
        const uint2* p = (const uint2*)vr;
#pragma unroll
        for (int i = 0; i < 5; ++i) ((uint2*)tmp)[i] = p[i];
#pragma unroll
        for (int d = 0; d < 20; ++d) Vt[d * VSTR + tid] = tmp[d];
#pragma unroll
        for (int d = 20; d < 32; ++d) Vt[d * VSTR + tid] = 0;
    }
    __syncthreads();

    // Q B-frags (q pre-scaled by SCALE2 in mm<0>)
    bf16x8 bq[4];
#pragma unroll
    for (int nt = 0; nt < 4; ++nt)
        bq[nt] = load_frag20(qpl + (size_t)(qoff + wave * 64 + nt * 16 + l16) * 20, quad);

    f32x4 accO[4][2];
#pragma unroll
    for (int nt = 0; nt < 4; ++nt) {
        accO[nt][0] = (f32x4){0.f, 0.f, 0.f, 0.f};
        accO[nt][1] = (f32x4){0.f, 0.f, 0.f, 0.f};
    }
    float mst[4] = {-1e30f, -1e30f, -1e30f, -1e30f};
    float lst[4] = {0.f, 0.f, 0.f, 0.f};
    const f32x4 z4 = {0.f, 0.f, 0.f, 0.f};

#pragma unroll
    for (int kt = 0; kt < NK / 32; ++kt) {
        bf16x8 ak0 = load_frag20(kpl + (size_t)(koff + kt * 32 + l16) * 20, quad);
        bf16x8 ak1 = load_frag20(kpl + (size_t)(koff + kt * 32 + 16 + l16) * 20, quad);
        bf16x8 av0 = *(const bf16x8*)(Vt + (size_t)l16 * VSTR + kt * 32 + quad * 8);
        bf16x8 av1 = *(const bf16x8*)(Vt + (size_t)(16 + l16) * VSTR + kt * 32 + quad * 8);

        f32x4 s0[4], s1[4];
#pragma unroll
        for (int nt = 0; nt < 4; ++nt) {
            s0[nt] = __builtin_amdgcn_mfma_f32_16x16x32_bf16(ak0, bq[nt], z4, 0, 0, 0);
            s1[nt] = __builtin_amdgcn_mfma_f32_16x16x32_bf16(ak1, bq[nt], z4, 0, 0, 0);
        }
#pragma unroll
        for (int nt = 0; nt < 4; ++nt) {
            float t = fmaxf(fmaxf(fmaxf(s0[nt][0], s0[nt][1]), fmaxf(s0[nt][2], s0[nt][3])),
                            fmaxf(fmaxf(s1[nt][0], s1[nt][1]), fmaxf(s1[nt][2], s1[nt][3])));
            t = fmaxf(t, __shfl_xor(t, 16, 64));
            t = fmaxf(t, __shfl_xor(t, 32, 64));
            float mnew = fmaxf(mst[nt], t);
            float alpha = exp2f(mst[nt] - mnew);
            mst[nt] = mnew;
            float p0 = exp2f(s0[nt][0] - mnew), p1 = exp2f(s0[nt][1] - mnew);
            float p2 = exp2f(s0[nt][2] - mnew), p3 = exp2f(s0[nt][3] - mnew);
            float p4 = exp2f(s1[nt][0] - mnew), p5 = exp2f(s1[nt][1] - mnew);
            float p6 = exp2f(s1[nt][2] - mnew), p7 = exp2f(s1[nt][3] - mnew);
            float ts = ((p0 + p1) + (p2 + p3)) + ((p4 + p5) + (p6 + p7));
            ts += __shfl_xor(ts, 16, 64);
            ts += __shfl_xor(ts, 32, 64);
            lst[nt] = lst[nt] * alpha + ts;
            accO[nt][0] *= alpha;
            accO[nt][1] *= alpha;
            // P^T B-frag: keys quad*8+j, query l16 (bpermute from S^T C-layout)
            unsigned pk00 = packbf(p0, p1), pk01 = packbf(p2, p3);
            unsigned pk10 = packbf(p4, p5), pk11 = packbf(p6, p7);
            int src0 = ((quad & 1) << 5) + l16;
            int src1 = src0 + 16;
            unsigned x00 = __shfl(pk00, src0, 64), y00 = __shfl(pk10, src0, 64);
            unsigned x01 = __shfl(pk01, src0, 64), y01 = __shfl(pk11, src0, 64);
            unsigned x10 = __shfl(pk00, src1, 64), y10 = __shfl(pk10, src1, 64);
            unsigned x11 = __shfl(pk01, src1, 64), y11 = __shfl(pk11, src1, 64);
            bool hi = quad >= 2;
            B8U bp;
            bp.u[0] = hi ? y00 : x00;
            bp.u[1] = hi ? y01 : x01;
            bp.u[2] = hi ? y10 : x10;
            bp.u[3] = hi ? y11 : x11;
            accO[nt][0] = __builtin_amdgcn_mfma_f32_16x16x32_bf16(av0, bp.v, accO[nt][0], 0, 0, 0);
            accO[nt][1] = __builtin_amdgcn_mfma_f32_16x16x32_bf16(av1, bp.v, accO[nt][1], 0, 0, 0);
        }
    }

    // epilogue: O^T C-layout -> lane l16 = query, dims = dt*16 + quad*4 + r
#pragma unroll
    for (int nt = 0; nt < 4; ++nt) {
        float inv = 1.f / lst[nt];
        int tok = (MUT ? half * 128 : 0) + wave * 64 + nt * 16 + l16;
        short* orow = xout + (size_t)(wl * 256 + tok) * 240 + (MUT ? hd * 20 : 120 + hd * 20);
        unsigned lo = packbf(accO[nt][0][0] * inv, accO[nt][0][1] * inv);
        unsigned hi2 = packbf(accO[nt][0][2] * inv, accO[nt][0][3] * inv);
        *(uint2*)(orow + quad * 4) = make_uint2(lo, hi2);
        if (quad == 0) {
            unsigned lo2 = packbf(accO[nt][1][0] * inv, accO[nt][1][1] * inv);
            unsigned hi3 = packbf(accO[nt][1][2] * inv, accO[nt][1][3] * inv);
            *(uint2*)(orow + 16) = make_uint2(lo2, hi3);
        }
    }
}

// -------- Final remap: TMP fp32 (partitioned rows) -> d_out (global rows) ---
__global__ __launch_bounds__(256) void remap_out(const float* __restrict__ tmp,
                                                 float* __restrict__ out) {
    int idx = blockIdx.x * 256 + threadIdx.x;
    int r = idx / 60, p = idx % 60;
    int g = rev_row(r);
    *(float2*)(out + (size_t)g * 120 + p * 2) =
        *(const float2*)(tmp + (size_t)r * 120 + p * 2);
}

extern "C" void kernel_launch(void* const* d_in, const int* in_sizes, int n_in,
                              void* d_out, int out_size, void* d_ws, size_t ws_size,
                              hipStream_t stream) {
    const float* x          = (const float*)d_in[0];
    const float* norm1_w    = (const float*)d_in[1];
    const float* norm1_b    = (const float*)d_in[2];
    const float* qkv_self_w = (const float*)d_in[3];
    const float* qkv_self_b = (const float*)d_in[4];
    const float* qkv_mut_w  = (const float*)d_in[5];
    const float* qkv_mut_b  = (const float*)d_in[6];
    const float* proj_w     = (const float*)d_in[7];
    const float* proj_b     = (const float*)d_in[8];
    const float* norm2_w    = (const float*)d_in[9];
    const float* norm2_b    = (const float*)d_in[10];
    const float* fc11_w     = (const float*)d_in[11];
    const float* fc11_b     = (const float*)d_in[12];
    const float* fc12_w     = (const float*)d_in[13];
    const float* fc12_b     = (const float*)d_in[14];
    const float* fc2_w      = (const float*)d_in[15];
    const float* fc2_b      = (const float*)d_in[16];

    if (ws_size < 110100480u) return;

    char* wsb   = (char*)d_ws;
    short* Hb    = (short*)wsb;                  // 131072x120 bf16
    short* QKVc  = (short*)(wsb + 31457280);     // 3 planes, chunk
    short* XOUTc = (short*)(wsb + 78643200);     // 65536x240 bf16
    float* TMP   = (float*)wsb;                  // 131072x120 fp32 (MLP phase)
    short* H2c   = (short*)(wsb + 62914560);     // 65536x120 bf16
    short* HIDc  = (short*)(wsb + 78643200);     // 65536x240 bf16
    float* X2    = (float*)d_out;                // partitioned residual fp32

    // 1. LN1 + window partition -> Hb (bf16)
    ln_kernel<true><<<32768, 256, 0, stream>>>(x, norm1_w, norm1_b, Hb);

    // 2. Attention phase: 2 chunks x 256 windows (65536 rows)
    for (int c = 0; c < 2; ++c) {
        int m0 = c * CHROWS;
        const short* Ac = Hb + (size_t)m0 * 120;
        mm<0, 120, 360><<<dim3(512, 6), 256, 0, stream>>>(Ac, qkv_self_w, qkv_self_b,
                                                          QKVc, nullptr, 0);
        attn_flash<256, false><<<1536, 256, 0, stream>>>(QKVc, XOUTc);
        mm<0, 120, 360><<<dim3(512, 6), 256, 0, stream>>>(Ac, qkv_mut_w, qkv_mut_b,
                                                          QKVc, nullptr, 0);
        attn_flash<128, true><<<3072, 128, 0, stream>>>(QKVc, XOUTc);
        mm<1, 240, 120><<<dim3(512, 2), 256, 0, stream>>>(XOUTc, proj_w, proj_b,
                                                          X2, x, m0);
    }

    // 3. MLP phase: 2 chunks x 65536 rows
    for (int c = 0; c < 2; ++c) {
        int m0 = c * CHROWS;
        ln_kernel<false><<<16384, 256, 0, stream>>>(X2 + (size_t)m0 * 120,
                                                    norm2_w, norm2_b, H2c);
        mm<2, 120, 240><<<dim3(512, 4), 256, 0, stream>>>(H2c, fc11_w, fc11_b,
                                                          HIDc, nullptr, 0);
        mm<3, 120, 240><<<dim3(512, 4), 256, 0, stream>>>(H2c, fc12_w, fc12_b,
                                                          HIDc, nullptr, 0);
        mm<4, 240, 120><<<dim3(512, 2), 256, 0, stream>>>(HIDc, fc2_w, fc2_b,
                                                          TMP, X2, m0);
    }

    // 4. Window-reverse TMP -> d_out
    remap_out<<<30720, 256, 0, stream>>>(TMP, (float*)d_out);
}

// Round 5
// 800.239 us; speedup vs baseline: 2.8891x; 1.0458x over previous
//
#include <hip/hip_runtime.h>
#include <hip/hip_bf16.h>
#include <math.h>

// TMSA R5: zero-shuffle flash attention (interleaved-key S^T), no-max softmax,
// packed-u32 V^T LDS (conflict-free), fc2 scatter-writes d_out directly.
//
// ws (bytes), guard 110,100,480:
//   attn phase: Hb bf16 [0,31457280) | QKVc bf16 [31457280,78643200)
//               XOUTc bf16 [78643200,110100480)
//   mlp  phase: TMP fp32 [0,62914560) (d2d copy of X2) |
//               H2c bf16 [62914560,78643200) | HIDc bf16 [78643200,110100480)
//   X2 (fp32, partitioned) lives in d_out mid-pipeline; fc2 writes d_out at
//   rev_row directly (residual read from TMP -> no alias race).

typedef __attribute__((ext_vector_type(8))) short bf16x8;
typedef __attribute__((ext_vector_type(4))) float f32x4;

#define SCALE2 (0.22360679774997896f * 1.44269504088896340f)  // d^-0.5 * log2(e)
#define CHROWS 65536
#define QPLANE 7864320u   // 65536*120 elems per q/k/v plane (chunk)

union B8U { bf16x8 v; uint2 u2[2]; unsigned u[4]; short s[8]; };

__device__ __forceinline__ short bf16b(float f) {
    __hip_bfloat16 h = __float2bfloat16(f);
    return *reinterpret_cast<short*>(&h);
}
__device__ __forceinline__ float bf2f(short s) {
    return __uint_as_float(((unsigned)(unsigned short)s) << 16);
}
__device__ __forceinline__ unsigned packbf(float a, float b) {
    return (unsigned)(unsigned short)bf16b(a) |
           ((unsigned)(unsigned short)bf16b(b) << 16);
}

// partitioned row r -> global row g
__device__ __forceinline__ int rev_row(int r) {
    int w = r >> 8, t = r & 255;
    int w8 = w & 7, h8 = (w >> 3) & 7, d2 = (w >> 6) & 1, n2 = w >> 7;
    int www = t & 7, hh = (t >> 3) & 7, dd = (t >> 6) & 1, nn = t >> 7;
    int n = n2 * 2 + nn, d = d2 * 2 + dd;
    int Hc = h8 * 8 + hh, Wc = w8 * 8 + www;
    return ((n * 4 + d) << 12) + (Hc << 6) + Wc;
}
// global row g -> partitioned row
__device__ __forceinline__ int part_row(int g) {
    int ww = g & 63, hh = (g >> 6) & 63, d = (g >> 12) & 3, n = g >> 14;
    int w = ((n >> 1) * 2 + (d >> 1)) * 64 + ((hh >> 3) << 3) + (ww >> 3);
    int t = (((n & 1) * 2 + (d & 1)) << 6) + ((hh & 7) << 3) + (ww & 7);
    return (w << 8) + t;
}
__device__ __forceinline__ float gelu_exact(float x) {
    return 0.5f * x * (1.0f + erff(x * 0.70710678118654752f));
}

// load A/B-frag from a 20-elem bf16 row (stride 20), k = quad*8..quad*8+7,
// zero-padded for k >= 20. 8B-aligned uint2 loads.
__device__ __forceinline__ bf16x8 load_frag20(const short* row, int quad) {
    B8U r;
    const uint2* p = (const uint2*)(row + quad * 8);
    r.u2[0] = p[0]; r.u2[1] = p[1];
    if (quad == 2) { r.u[2] = 0; r.u[3] = 0; }
    else if (quad == 3) { r.u[0] = r.u[1] = r.u[2] = r.u[3] = 0; }
    return r.v;
}

// ---------------- LayerNorm (C=120) fp32 in -> bf16 out ---------------------
template <bool REMAP>
__global__ __launch_bounds__(256) void ln_kernel(const float* __restrict__ in,
                                                 const float* __restrict__ w,
                                                 const float* __restrict__ b,
                                                 short* __restrict__ out) {
    int row  = blockIdx.x * 4 + (threadIdx.x >> 6);
    int lane = threadIdx.x & 63;
    const float* xr = in + (size_t)row * 120;
    float2 v = make_float2(0.f, 0.f);
    if (lane < 60) v = *(const float2*)(xr + lane * 2);
    float s = v.x + v.y;
#pragma unroll
    for (int off = 32; off; off >>= 1) s += __shfl_down(s, off, 64);
    s = __shfl(s, 0, 64);
    float mean = s * (1.f / 120.f);
    float dx = v.x - mean, dy = v.y - mean;
    float q = (lane < 60) ? (dx * dx + dy * dy) : 0.f;
#pragma unroll
    for (int off = 32; off; off >>= 1) q += __shfl_down(q, off, 64);
    q = __shfl(q, 0, 64);
    float rstd = rsqrtf(q * (1.f / 120.f) + 1e-5f);
    int orow = REMAP ? part_row(row) : row;
    if (lane < 60) {
        float2 wv = *(const float2*)(w + lane * 2);
        float2 bv = *(const float2*)(b + lane * 2);
        unsigned u = packbf(dx * rstd * wv.x + bv.x, dy * rstd * wv.y + bv.y);
        *(unsigned*)(out + (size_t)orow * 120 + lane * 2) = u;
    }
}

// ------------- MFMA GEMM: out = A(M x K, bf16) @ W(N x K, fp32)^T + bias ----
// MODE: 0 QKV scatter (q pre-scaled by SCALE2) | 1 proj(+x res -> X2 fp32)
//       2 gelu bf16 | 3 multiply-into bf16 | 4 fc2(+TMP res -> d_out @rev_row)
template <int MODE, int K, int N>
__global__ __launch_bounds__(256) void mm(const short* __restrict__ A,
                                          const float* __restrict__ W,
                                          const float* __restrict__ bias,
                                          void* __restrict__ outp,
                                          const float* __restrict__ aux,
                                          int m0) {
    const int lane = threadIdx.x & 63, wave = threadIdx.x >> 6;
    const int quad = lane >> 4, l16 = lane & 15;
    const int bm = blockIdx.x * 128 + (wave >> 1) * 64;
    const int bn = blockIdx.y * 64 + (wave & 1) * 32;

    f32x4 acc[4][2];
#pragma unroll
    for (int i = 0; i < 4; ++i)
#pragma unroll
        for (int j = 0; j < 2; ++j) acc[i][j] = (f32x4){0.f, 0.f, 0.f, 0.f};

    const short* Ar[4];
#pragma unroll
    for (int i = 0; i < 4; ++i) Ar[i] = A + (size_t)(bm + i * 16 + l16) * K;
    const int n0 = bn + l16, n1 = bn + 16 + l16;
    const int nc0 = n0 < N ? n0 : N - 1;
    const int nc1 = n1 < N ? n1 : N - 1;
    const float* W0 = W + (size_t)nc0 * K;
    const float* W1 = W + (size_t)nc1 * K;

    const int KT = (K + 31) / 32;
#pragma unroll
    for (int kt = 0; kt < KT; ++kt) {
        int kk = kt * 32 + quad * 8;
        bool kok = kk < K;
        int kc = kok ? kk : 0;
        bf16x8 a[4], b0v, b1v;
#pragma unroll
        for (int i = 0; i < 4; ++i) a[i] = *(const bf16x8*)(Ar[i] + kc);
        {
            f32x4 w0 = *(const f32x4*)(W0 + kc);
            f32x4 w1 = *(const f32x4*)(W0 + kc + 4);
            b0v = (bf16x8){bf16b(w0.x), bf16b(w0.y), bf16b(w0.z), bf16b(w0.w),
                           bf16b(w1.x), bf16b(w1.y), bf16b(w1.z), bf16b(w1.w)};
            f32x4 w2 = *(const f32x4*)(W1 + kc);
            f32x4 w3 = *(const f32x4*)(W1 + kc + 4);
            b1v = (bf16x8){bf16b(w2.x), bf16b(w2.y), bf16b(w2.z), bf16b(w2.w),
                           bf16b(w3.x), bf16b(w3.y), bf16b(w3.z), bf16b(w3.w)};
        }
        if (!kok) {
            bf16x8 zz = {0, 0, 0, 0, 0, 0, 0, 0};
            a[0] = a[1] = a[2] = a[3] = b0v = b1v = zz;
        }
#pragma unroll
        for (int i = 0; i < 4; ++i) {
            acc[i][0] = __builtin_amdgcn_mfma_f32_16x16x32_bf16(a[i], b0v, acc[i][0], 0, 0, 0);
            acc[i][1] = __builtin_amdgcn_mfma_f32_16x16x32_bf16(a[i], b1v, acc[i][1], 0, 0, 0);
        }
    }

#pragma unroll
    for (int j = 0; j < 2; ++j) {
        const int n = j ? n1 : n0;
        if (n >= N) continue;
        const float bs = bias[n];
        int which = 0, head = 0, e = 0;
        if (MODE == 0) { which = n / 120; int hn = n % 120; head = hn / 20; e = hn % 20; }
#pragma unroll
        for (int i = 0; i < 4; ++i) {
#pragma unroll
            for (int r = 0; r < 4; ++r) {
                int m = bm + i * 16 + quad * 4 + r;
                float val = acc[i][j][r] + bs;
                if (MODE == 0) {
                    if (which == 0) val *= SCALE2;
                    int wl = m >> 8, t = m & 255;
                    ((short*)outp)[(size_t)which * QPLANE +
                                   ((size_t)((wl * 6 + head) * 256 + t)) * 20 + e] = bf16b(val);
                } else if (MODE == 1) {
                    int g = rev_row(m0 + m);
                    val += aux[(size_t)g * 120 + n];
                    ((float*)outp)[(size_t)(m0 + m) * 120 + n] = val;
                } else if (MODE == 2) {
                    ((short*)outp)[(size_t)m * 240 + n] = bf16b(gelu_exact(val));
                } else if (MODE == 3) {
                    size_t idx = (size_t)m * 240 + n;
                    short* o = (short*)outp;
                    o[idx] = bf16b(bf2f(o[idx]) * val);
                } else { // MODE 4: aux pre-offset by m0*120; scatter to d_out
                    int g = rev_row(m0 + m);
                    val += aux[(size_t)m * 120 + n];
                    ((float*)outp)[(size_t)g * 120 + n] = val;
                }
            }
        }
    }
}

// ---------------- MFMA flash attention, zero-shuffle ------------------------
// S^T = mfma(A=K[perm rows], B=Q): C regs at lane(quad,l16) hold exactly the
// P^T B-frag keys (quad*8+0..3 from s0, +4..7 from s1) for query l16.
// No-max softmax (scores bounded, scale*log2e folded into q): p=exp2(s),
// l deferred to epilogue (2 shfl_xor). V^T staged as packed u32 dim-pairs.
template <int NK, bool MUT>
__global__ __launch_bounds__(NK) void attn_flash(const short* __restrict__ qkv,
                                                 short* __restrict__ xout) {
    constexpr int VSTR2 = NK + 4;                 // u32 stride (16B-aligned rows)
    __shared__ __align__(16) unsigned Vt2[16 * VSTR2];
    const int b = blockIdx.x;
    int wl, hd, half;
    if (MUT) { half = b & 1; hd = (b >> 1) % 6; wl = b / 12; }
    else     { half = 0;     hd = b % 6;        wl = b / 6;  }
    const int tid  = threadIdx.x;
    const int lane = tid & 63, wave = tid >> 6;
    const int quad = lane >> 4, l16 = lane & 15;

    const size_t rb = (size_t)(wl * 6 + hd) * 256;
    const short* qpl = qkv + rb * 20;
    const short* kpl = qkv + (size_t)QPLANE + rb * 20;
    const short* vpl = qkv + 2 * (size_t)QPLANE + rb * 20;
    const int koff = MUT ? half * 128 : 0;
    const int qoff = MUT ? (1 - half) * 128 : 0;

    // stage V^T as u32 dim-pairs: Vt2[d2][key] = dims(2*d2, 2*d2+1)
    {
        const uint2* p = (const uint2*)(vpl + (size_t)(koff + tid) * 20);
        unsigned tmp[10];
#pragma unroll
        for (int i = 0; i < 5; ++i) ((uint2*)tmp)[i] = p[i];
#pragma unroll
        for (int i = 0; i < 10; ++i) Vt2[i * VSTR2 + tid] = tmp[i];
#pragma unroll
        for (int i = 10; i < 16; ++i) Vt2[i * VSTR2 + tid] = 0;
    }
    __syncthreads();

    // Q B-frags (pre-scaled by SCALE2 in mm<0>)
    bf16x8 bq[4];
#pragma unroll
    for (int nt = 0; nt < 4; ++nt)
        bq[nt] = load_frag20(qpl + (size_t)(qoff + wave * 64 + nt * 16 + l16) * 20, quad);

    // permuted K row pointers: s0 keys = (l16>>2)*8 + (l16&3), s1 = +4
    const int krow = koff + ((l16 >> 2) << 3) + (l16 & 3);
    const short* kp0 = kpl + (size_t)krow * 20;
    const short* kp1 = kp0 + 4 * 20;

    const unsigned sel = (l16 & 1) ? 0x07060302u : 0x05040100u;
    const unsigned* vbase0 = Vt2 + (l16 >> 1) * VSTR2;
    const unsigned* vbase1 = Vt2 + (8 + (l16 >> 1)) * VSTR2;

    f32x4 accO[4][2];
#pragma unroll
    for (int nt = 0; nt < 4; ++nt) {
        accO[nt][0] = (f32x4){0.f, 0.f, 0.f, 0.f};
        accO[nt][1] = (f32x4){0.f, 0.f, 0.f, 0.f};
    }
    float lst[4] = {0.f, 0.f, 0.f, 0.f};
    const f32x4 z4 = {0.f, 0.f, 0.f, 0.f};

#pragma unroll
    for (int kt = 0; kt < NK / 32; ++kt) {
        bf16x8 ak0 = load_frag20(kp0 + (size_t)kt * 32 * 20, quad);
        bf16x8 ak1 = load_frag20(kp1 + (size_t)kt * 32 * 20, quad);
        // V^T A-frags from packed LDS: 2x b128 + 4 perm each
        B8U av0, av1;
        {
            uint4 va = *(const uint4*)(vbase0 + kt * 32 + quad * 8);
            uint4 vb = *(const uint4*)(vbase0 + kt * 32 + quad * 8 + 4);
            av0.u[0] = __builtin_amdgcn_perm(va.y, va.x, sel);
            av0.u[1] = __builtin_amdgcn_perm(va.w, va.z, sel);
            av0.u[2] = __builtin_amdgcn_perm(vb.y, vb.x, sel);
            av0.u[3] = __builtin_amdgcn_perm(vb.w, vb.z, sel);
            uint4 vc = *(const uint4*)(vbase1 + kt * 32 + quad * 8);
            uint4 vd = *(const uint4*)(vbase1 + kt * 32 + quad * 8 + 4);
            av1.u[0] = __builtin_amdgcn_perm(vc.y, vc.x, sel);
            av1.u[1] = __builtin_amdgcn_perm(vc.w, vc.z, sel);
            av1.u[2] = __builtin_amdgcn_perm(vd.y, vd.x, sel);
            av1.u[3] = __builtin_amdgcn_perm(vd.w, vd.z, sel);
        }
#pragma unroll
        for (int nt = 0; nt < 4; ++nt) {
            f32x4 s0 = __builtin_amdgcn_mfma_f32_16x16x32_bf16(ak0, bq[nt], z4, 0, 0, 0);
            f32x4 s1 = __builtin_amdgcn_mfma_f32_16x16x32_bf16(ak1, bq[nt], z4, 0, 0, 0);
            float p0 = __builtin_amdgcn_exp2f(s0[0]), p1 = __builtin_amdgcn_exp2f(s0[1]);
            float p2 = __builtin_amdgcn_exp2f(s0[2]), p3 = __builtin_amdgcn_exp2f(s0[3]);
            float p4 = __builtin_amdgcn_exp2f(s1[0]), p5 = __builtin_amdgcn_exp2f(s1[1]);
            float p6 = __builtin_amdgcn_exp2f(s1[2]), p7 = __builtin_amdgcn_exp2f(s1[3]);
            lst[nt] += ((p0 + p1) + (p2 + p3)) + ((p4 + p5) + (p6 + p7));
            B8U bp;   // P^T B-frag: j=0..3 <- s0 regs (keys q*8+r), j=4..7 <- s1 (+4)
            bp.u[0] = packbf(p0, p1);
            bp.u[1] = packbf(p2, p3);
            bp.u[2] = packbf(p4, p5);
            bp.u[3] = packbf(p6, p7);
            accO[nt][0] = __builtin_amdgcn_mfma_f32_16x16x32_bf16(av0.v, bp.v, accO[nt][0], 0, 0, 0);
            accO[nt][1] = __builtin_amdgcn_mfma_f32_16x16x32_bf16(av1.v, bp.v, accO[nt][1], 0, 0, 0);
        }
    }

    // epilogue: O^T C-layout (col l16=query, row quad*4+r=dim); reduce l over quads
#pragma unroll
    for (int nt = 0; nt < 4; ++nt) {
        float l = lst[nt];
        l += __shfl_xor(l, 16, 64);
        l += __shfl_xor(l, 32, 64);
        float inv = 1.f / l;
        int tok = (MUT ? half * 128 : 0) + wave * 64 + nt * 16 + l16;
        short* orow = xout + (size_t)(wl * 256 + tok) * 240 + (MUT ? hd * 20 : 120 + hd * 20);
        unsigned lo = packbf(accO[nt][0][0] * inv, accO[nt][0][1] * inv);
        unsigned hi2 = packbf(accO[nt][0][2] * inv, accO[nt][0][3] * inv);
        *(uint2*)(orow + quad * 4) = make_uint2(lo, hi2);
        if (quad == 0) {
            unsigned lo2 = packbf(accO[nt][1][0] * inv, accO[nt][1][1] * inv);
            unsigned hi3 = packbf(accO[nt][1][2] * inv, accO[nt][1][3] * inv);
            *(uint2*)(orow + 16) = make_uint2(lo2, hi3);
        }
    }
}

extern "C" void kernel_launch(void* const* d_in, const int* in_sizes, int n_in,
                              void* d_out, int out_size, void* d_ws, size_t ws_size,
                              hipStream_t stream) {
    const float* x          = (const float*)d_in[0];
    const float* norm1_w    = (const float*)d_in[1];
    const float* norm1_b    = (const float*)d_in[2];
    const float* qkv_self_w = (const float*)d_in[3];
    const float* qkv_self_b = (const float*)d_in[4];
    const float* qkv_mut_w  = (const float*)d_in[5];
    const float* qkv_mut_b  = (const float*)d_in[6];
    const float* proj_w     = (const float*)d_in[7];
    const float* proj_b     = (const float*)d_in[8];
    const float* norm2_w    = (const float*)d_in[9];
    const float* norm2_b    = (const float*)d_in[10];
    const float* fc11_w     = (const float*)d_in[11];
    const float* fc11_b     = (const float*)d_in[12];
    const float* fc12_w     = (const float*)d_in[13];
    const float* fc12_b     = (const float*)d_in[14];
    const float* fc2_w      = (const float*)d_in[15];
    const float* fc2_b      = (const float*)d_in[16];

    if (ws_size < 110100480u) return;

    char* wsb   = (char*)d_ws;
    short* Hb    = (short*)wsb;                  // 131072x120 bf16
    short* QKVc  = (short*)(wsb + 31457280);     // 3 planes, chunk
    short* XOUTc = (short*)(wsb + 78643200);     // 65536x240 bf16
    float* TMP   = (float*)wsb;                  // X2 copy, fp32 (MLP phase)
    short* H2c   = (short*)(wsb + 62914560);     // 65536x120 bf16
    short* HIDc  = (short*)(wsb + 78643200);     // 65536x240 bf16
    float* X2    = (float*)d_out;                // partitioned residual fp32
    float* out   = (float*)d_out;

    // 1. LN1 + window partition -> Hb (bf16)
    ln_kernel<true><<<32768, 256, 0, stream>>>(x, norm1_w, norm1_b, Hb);

    // 2. Attention phase: 2 chunks x 256 windows
    for (int c = 0; c < 2; ++c) {
        int m0 = c * CHROWS;
        const short* Ac = Hb + (size_t)m0 * 120;
        mm<0, 120, 360><<<dim3(512, 6), 256, 0, stream>>>(Ac, qkv_self_w, qkv_self_b,
                                                          QKVc, nullptr, 0);
        attn_flash<256, false><<<1536, 256, 0, stream>>>(QKVc, XOUTc);
        mm<0, 120, 360><<<dim3(512, 6), 256, 0, stream>>>(Ac, qkv_mut_w, qkv_mut_b,
                                                          QKVc, nullptr, 0);
        attn_flash<128, true><<<3072, 128, 0, stream>>>(QKVc, XOUTc);
        mm<1, 240, 120><<<dim3(512, 2), 256, 0, stream>>>(XOUTc, proj_w, proj_b,
                                                          X2, x, m0);
    }

    // 3. X2 -> TMP (frees d_out for scatter writes; residual source)
    hipMemcpyAsync(TMP, d_out, 62914560u, hipMemcpyDeviceToDevice, stream);

    // 4. MLP phase: 2 chunks x 65536 rows; fc2 scatters straight into d_out
    for (int c = 0; c < 2; ++c) {
        int m0 = c * CHROWS;
        ln_kernel<false><<<16384, 256, 0, stream>>>(TMP + (size_t)m0 * 120,
                                                    norm2_w, norm2_b, H2c);
        mm<2, 120, 240><<<dim3(512, 4), 256, 0, stream>>>(H2c, fc11_w, fc11_b,
                                                          HIDc, nullptr, 0);
        mm<3, 120, 240><<<dim3(512, 4), 256, 0, stream>>>(H2c, fc12_w, fc12_b,
                                                          HIDc, nullptr, 0);
        mm<4, 240, 120><<<dim3(512, 2), 256, 0, stream>>>(HIDc, fc2_w, fc2_b,
                                                          out, TMP + (size_t)m0 * 120, m0);
    }
}